// Round 1
// 190.405 us; speedup vs baseline: 1.0817x; 1.0817x over previous
//
#include <hip/hip_runtime.h>

// entmax-1.5 attention, round 7: 3-blocks/CU LDS diet + XOR-swizzled LDS.
// B=4 H=8 S=1024 D=128. Pre: K->bf16 [bh][key][d]; V->bf16 [bh][d][key].
// Main: 2048 blocks (32 bh x 64 q-tiles of 16 rows), 512 thr (8 waves).
// LDS = sc 32K + kv 16K + q_s 4K = 53,248 B -> 3 blocks/CU (24 waves).
// All LDS tiles un-padded, bank conflicts killed by 16B-chunk XOR swizzle
// (chunk ^= row&7) applied consistently on write and read.
// Phase 1: QK^T in 64-wide d-halves (acc accumulates across halves).
// Phase 2: 32 thr/row regather+mask+max+normalize; ballot-compact {x > -1}
//          (tau* >= -1) into cand overlay on kv (CCAP=256); 14-iter
//          bisection; fallback full register solve if cnt > 256 (also
//          covers all-masked rows). y written back dense to sc.
// Phase 3: O = P @ V^T in 64-key halves, same swizzled fragments.

#define S_ 1024
#define D_ 128
#define NEG_INF_F (-1.0e12f)
#define SCALE_F 0.08838834764831845f  // 1/sqrt(128)
#define NITER 14                      // dTau=6e-5 -> out err ~1e-3 << 0.0766
#define CCAP 256                      // candidate cap per row (expected ~50)

typedef float f32x4 __attribute__((ext_vector_type(4)));
typedef short short8 __attribute__((ext_vector_type(8)));

__device__ __forceinline__ ushort f2bf(float x) {   // RNE f32 -> bf16
    unsigned u = __builtin_bit_cast(unsigned, x);
    u += 0x7FFFu + ((u >> 16) & 1u);
    return (ushort)(u >> 16);
}
__device__ __forceinline__ float bf2f(ushort h) {
    unsigned u = ((unsigned)h) << 16;
    return __builtin_bit_cast(float, u);
}

// ---- fused pre-kernel: blocks 0..4095 K->bf16; 4096..5119 V->bf16-T ----
// V transpose via write-side scatter (scalar LDS writes ~4-way) instead of
// read-side gather (was 16-way conflicted): store tileT[d][key] directly.
__global__ __launch_bounds__(256)
void pre_cvt(const float* __restrict__ K, const float* __restrict__ V,
             ushort* __restrict__ Kb, ushort* __restrict__ Vt)
{
    __shared__ __align__(16) ushort tileT[64][68];  // [d][key], pad->8B rows
    const int t = threadIdx.x;
    if (blockIdx.x < 4096) {                        // K convert (coalesced)
        int i = blockIdx.x * 256 + t;               // 1,048,576 float4s
        float4 v = ((const float4*)K)[i];
        ushort4 o;
        o.x = f2bf(v.x); o.y = f2bf(v.y); o.z = f2bf(v.z); o.w = f2bf(v.w);
        ((ushort4*)Kb)[i] = o;
        return;
    }
    // V transpose: 64x64 tile per block. 1024 blocks = 32 bh x 16 kt x 2 dh
    const int vb = blockIdx.x - 4096;
    const int bh = vb >> 5, r5 = vb & 31, kt = r5 >> 1, dh = r5 & 1;
    const float* src = V + ((size_t)(bh * S_ + kt * 64)) * D_ + dh * 64;
    #pragma unroll
    for (int i = 0; i < 4; ++i) {                   // 1024 float4 loads
        int idx = t + i * 256, r = idx >> 4, c = idx & 15;
        float4 vv = *(const float4*)(src + (size_t)r * D_ + c * 4);
        tileT[c * 4 + 0][r] = f2bf(vv.x);           // scatter-transpose
        tileT[c * 4 + 1][r] = f2bf(vv.y);
        tileT[c * 4 + 2][r] = f2bf(vv.z);
        tileT[c * 4 + 3][r] = f2bf(vv.w);
    }
    __syncthreads();
    ushort* dst = Vt + ((size_t)(bh * D_ + dh * 64)) * S_ + kt * 64;
    #pragma unroll
    for (int i = 0; i < 2; ++i) {                   // contiguous reads/stores
        int idx = t + i * 256, d = idx >> 3, jj = idx & 7;
        short8 val = *(const short8*)&tileT[d][jj * 8];
        *(short8*)(dst + (size_t)d * S_ + jj * 8) = val;
    }
}

// ---- main kernel --------------------------------------------------------
__global__ __launch_bounds__(512, 6)
void entmax_attn(const float* __restrict__ Q, const ushort* __restrict__ Kb,
                 const ushort* __restrict__ Vt, const int* __restrict__ M,
                 float* __restrict__ O)
{
    __shared__ __align__(16) ushort sc[16][1024];   // scores/P, swizzled
    __shared__ __align__(16) ushort kv[128][64];    // K/V^T half; cand overlay
    __shared__ __align__(16) ushort q_s[16][128];   // Q tile bf16, swizzled

    const int t = threadIdx.x;
    const int w = t >> 6, lane = t & 63, l = lane & 15, quad = lane >> 4;
    const int bh = blockIdx.x >> 6, qt = blockIdx.x & 63, b = bh >> 3;

    const ushort* kb_bh = Kb + (size_t)bh * S_ * D_;
    const ushort* vt_bh = Vt + (size_t)bh * D_ * S_;

    // staging: 128x64 half-tile = 1024 16B cells, 2 per thread
    const int sr0 = t >> 3, sch = t & 7, sr1 = sr0 + 64;
    ushort* kvw0 = &kv[sr0][(sch ^ (sr0 & 7)) << 3];
    ushort* kvw1 = &kv[sr1][(sch ^ (sr0 & 7)) << 3];   // sr1&7 == sr0&7

    // ---- stage Q tile (swizzled) + K half (kt0,d0..63); one barrier ----
    {
        const float4* qsrc = (const float4*)(Q + ((size_t)bh * S_ + (size_t)qt * 16) * D_);
        int r = t >> 5, c = t & 31;
        float4 v = qsrc[r * 32 + c];
        ushort4 o;
        o.x = f2bf(v.x); o.y = f2bf(v.y); o.z = f2bf(v.z); o.w = f2bf(v.w);
        *(ushort4*)&q_s[r][(((c >> 1) ^ (r & 7)) << 3) + ((c & 1) << 2)] = o;
    }
    short8 s0 = *(const short8*)(kb_bh + (size_t)sr0 * D_ + sch * 8);
    short8 s1 = *(const short8*)(kb_bh + (size_t)sr1 * D_ + sch * 8);
    *(short8*)kvw0 = s0;
    *(short8*)kvw1 = s1;
    __syncthreads();                                // q_s + K half 0 visible

    short8 aq[4];                                   // A[m=l][k=ks*32+quad*8+j]
    #pragma unroll
    for (int ks = 0; ks < 4; ++ks)
        aq[ks] = *(const short8*)&q_s[l][((ks * 4 + quad) ^ (l & 7)) << 3];

    // fragment pointers (rows n=d=w*16+l; chunks 0..7 swizzled by l&7)
    const int n = w * 16 + l;
    const ushort* kvA = &kv[n][(quad ^ (l & 7)) << 3];        // local ks 0
    const ushort* kvB = &kv[n][((4 + quad) ^ (l & 7)) << 3];  // local ks 1

    // ---- phase 1: QK^T, 8 key-tiles x 2 d-halves; acc spans halves -----
    #pragma unroll 1
    for (int kt = 0; kt < 8; ++kt) {
        f32x4 acc = {0.f, 0.f, 0.f, 0.f};
        #pragma unroll
        for (int kh = 0; kh < 2; ++kh) {
            const int h = kt * 2 + kh;
            if (h < 15) {                           // prefetch next half
                const int h2 = h + 1;
                const ushort* nb = kb_bh + (size_t)(h2 >> 1) * (128 * D_) + (h2 & 1) * 64;
                s0 = *(const short8*)(nb + (size_t)sr0 * D_ + sch * 8);
                s1 = *(const short8*)(nb + (size_t)sr1 * D_ + sch * 8);
            }
            __builtin_amdgcn_s_setprio(1);
            {
                short8 bk0 = *(const short8*)kvA;
                short8 bk1 = *(const short8*)kvB;
                acc = __builtin_amdgcn_mfma_f32_16x16x32_bf16(aq[kh * 2 + 0], bk0, acc, 0, 0, 0);
                acc = __builtin_amdgcn_mfma_f32_16x16x32_bf16(aq[kh * 2 + 1], bk1, acc, 0, 0, 0);
            }
            __builtin_amdgcn_s_setprio(0);
            if (kh == 1) {                          // scaled scores -> sc
                #pragma unroll
                for (int r = 0; r < 4; ++r) {
                    const int rr = quad * 4 + r, col = kt * 128 + n;
                    sc[rr][(((col >> 3) ^ (rr & 7)) << 3) + (col & 7)] =
                        f2bf(acc[r] * SCALE_F);
                }
            }
            __syncthreads();                        // kv reads done
            if (h < 15) {
                *(short8*)kvw0 = s0;
                *(short8*)kvw1 = s1;
                __syncthreads();                    // next half visible
            }
        }
    }

    // V^T half 0 into registers now (latency hides under solver)
    s0 = *(const short8*)(vt_bh + (size_t)sr0 * S_ + sch * 8);
    s1 = *(const short8*)(vt_bh + (size_t)sr1 * S_ + sch * 8);

    // ---- phase 2: regather + mask + max + normalize --------------------
    const int row = t >> 5, u = t & 31;             // 32 threads per row
    const int qg = qt * 16 + row;
    float x[32];
    #pragma unroll
    for (int c = 0; c < 4; ++c) {
        short8 v8 = *(const short8*)&sc[row][((c * 32 + u) ^ (row & 7)) << 3];
        #pragma unroll
        for (int e = 0; e < 8; ++e) x[c * 8 + e] = bf2f(((ushort*)&v8)[e]);
    }
    {   // mask: key = c*256 + u*8 + h*4 + e
        const int4* mrow = (const int4*)(M + ((size_t)b * S_ + qg) * S_);
        #pragma unroll
        for (int c = 0; c < 4; ++c) {
            #pragma unroll
            for (int h = 0; h < 2; ++h) {
                int4 mm = mrow[c * 64 + u * 2 + h];
                if (mm.x == 0) x[c * 8 + h * 4 + 0] = NEG_INF_F;
                if (mm.y == 0) x[c * 8 + h * 4 + 1] = NEG_INF_F;
                if (mm.z == 0) x[c * 8 + h * 4 + 2] = NEG_INF_F;
                if (mm.w == 0) x[c * 8 + h * 4 + 3] = NEG_INF_F;
            }
        }
    }
    float mx = -3.0e38f;
    #pragma unroll
    for (int j = 0; j < 32; ++j) mx = fmaxf(mx, x[j]);
    #pragma unroll
    for (int off = 1; off < 32; off <<= 1) mx = fmaxf(mx, __shfl_xor(mx, off));
    #pragma unroll
    for (int j = 0; j < 32; ++j) x[j] = (x[j] - mx) * 0.5f;   // x <= 0

    // ---- candidate compaction: exact set {x > -1} (tau* >= -1) ---------
    // cand overlays kv (dead until V store). 16 rows x 256 floats = 16 KB.
    float* cand = (float*)&kv[0][0];
    const unsigned long long halfmask =
        (lane >= 32) ? 0xFFFFFFFF00000000ull : 0x00000000FFFFFFFFull;
    int cnt = 0;
    #pragma unroll
    for (int j = 0; j < 32; ++j) {
        const bool p = (x[j] > -1.0f);
        unsigned long long bal = __ballot(p) & halfmask;
        if (p) {
            int pos = cnt + (int)__builtin_amdgcn_mbcnt_hi(
                (unsigned)(bal >> 32),
                __builtin_amdgcn_mbcnt_lo((unsigned)bal, 0));
            if (pos < CCAP) cand[row * CCAP + pos] = x[j];
        }
        cnt += __popcll(bal);
    }

    // ---- tau bisection on f(tau)=sum max(0,x-tau)^2=1, root in [-1,0] --
    float tau;
    if (cnt <= CCAP) {                              // compact path (normal)
        const float* crow = cand + row * CCAP;
        float lo = -1.f, hi = 0.f;
        #pragma unroll 1
        for (int it = 0; it < NITER; ++it) {
            const float tm = 0.5f * (lo + hi);
            float f = 0.f;
            for (int j = u; j < cnt; j += 32) {
                float d = fmaxf(crow[j] - tm, 0.f);
                f = fmaf(d, d, f);
            }
            #pragma unroll
            for (int off = 1; off < 32; off <<= 1) f += __shfl_xor(f, off);
            const bool ge = (f >= 1.f);
            lo = ge ? tm : lo;
            hi = ge ? hi : tm;
        }
        tau = 0.5f * (lo + hi);
    } else {                                        // fallback: full solve
        float lo = -1.f, hi = 0.f;
        #pragma unroll 1
        for (int it = 0; it < NITER; ++it) {
            const float tm = 0.5f * (lo + hi);
            float f = 0.f;
            #pragma unroll
            for (int j = 0; j < 32; ++j) {
                float d = fmaxf(x[j] - tm, 0.f);
                f = fmaf(d, d, f);
            }
            #pragma unroll
            for (int off = 1; off < 32; off <<= 1) f += __shfl_xor(f, off);
            const bool ge = (f >= 1.f);
            lo = ge ? tm : lo;
            hi = ge ? hi : tm;
        }
        tau = 0.5f * (lo + hi);
    }

    // ---- y = max(0,x-tau)^2 back into sc (dense, swizzled) -------------
    #pragma unroll
    for (int c = 0; c < 4; ++c) {
        short8 v8;
        #pragma unroll
        for (int e = 0; e < 8; ++e) {
            float d = fmaxf(x[c * 8 + e] - tau, 0.f);
            ((ushort*)&v8)[e] = f2bf(d * d);
        }
        *(short8*)&sc[row][((c * 32 + u) ^ (row & 7)) << 3] = v8;
    }
    __syncthreads();                                // cand reads + y done
    *(short8*)kvw0 = s0;                            // V^T half 0 -> kv
    *(short8*)kvw1 = s1;
    __syncthreads();                                // V half 0 + y visible

    // ---- phase 3: O = P @ V, 16 key-halves; wave w owns d w*16..+15 ----
    f32x4 oa = {0.f, 0.f, 0.f, 0.f};
    #pragma unroll 1
    for (int vh = 0; vh < 16; ++vh) {
        if (vh < 15) {                              // prefetch next half
            const ushort* nb = vt_bh + (size_t)(vh + 1) * 64;
            s0 = *(const short8*)(nb + (size_t)sr0 * S_ + sch * 8);
            s1 = *(const short8*)(nb + (size_t)sr1 * S_ + sch * 8);
        }
        __builtin_amdgcn_s_setprio(1);
        {
            short8 ap0 = *(const short8*)&sc[l][((vh * 8 + quad) ^ (l & 7)) << 3];
            short8 ap1 = *(const short8*)&sc[l][((vh * 8 + 4 + quad) ^ (l & 7)) << 3];
            short8 bv0 = *(const short8*)kvA;
            short8 bv1 = *(const short8*)kvB;
            oa = __builtin_amdgcn_mfma_f32_16x16x32_bf16(ap0, bv0, oa, 0, 0, 0);
            oa = __builtin_amdgcn_mfma_f32_16x16x32_bf16(ap1, bv1, oa, 0, 0, 0);
        }
        __builtin_amdgcn_s_setprio(0);
        __syncthreads();                            // kv reads done
        if (vh < 15) {
            *(short8*)kvw0 = s0;
            *(short8*)kvw1 = s1;
            __syncthreads();                        // next half visible
        }
    }

    // ---- epilogue: C/D map (col=d-within-slice=l, row=q=quad*4+r) ------
    float* ob = O + ((size_t)bh * S_ + (size_t)qt * 16) * D_;
    #pragma unroll
    for (int r = 0; r < 4; ++r)
        ob[(size_t)(quad * 4 + r) * D_ + w * 16 + l] = oa[r];
}

extern "C" void kernel_launch(void* const* d_in, const int* in_sizes, int n_in,
                              void* d_out, int out_size, void* d_ws, size_t ws_size,
                              hipStream_t stream) {
    const float* q = (const float*)d_in[0];
    const float* k = (const float*)d_in[1];
    const float* v = (const float*)d_in[2];
    const int*   m = (const int*)d_in[3];
    float*       o = (float*)d_out;

    ushort* Kb = (ushort*)d_ws;                      // 8,388,608 B
    ushort* Vt = (ushort*)((char*)d_ws + 8388608);   // 8,388,608 B

    pre_cvt<<<5120, 256, 0, stream>>>(k, v, Kb, Vt);
    entmax_attn<<<2048, 512, 0, stream>>>(q, Kb, Vt, m, o);
}